// Round 8
// baseline (632.438 us; speedup 1.0000x reference)
//
#include <hip/hip_runtime.h>
#include <hip/hip_bf16.h>
#include <math.h>

#define B1 2048
#define B2 8192
#define NH 12
#define DH 64
#define DMODEL 768

typedef __attribute__((ext_vector_type(8))) short short8;
typedef __attribute__((ext_vector_type(4))) float floatx4;
typedef __attribute__((ext_vector_type(8))) unsigned short ushort8;
typedef __attribute__((ext_vector_type(4))) unsigned short ushort4v;

static __device__ __forceinline__ unsigned short f2bf(float f) {
  __bf16 b = (__bf16)f;
  return __builtin_bit_cast(unsigned short, b);
}
static __device__ __forceinline__ float bf2f(unsigned short u) {
  return __builtin_bit_cast(float, ((unsigned)u) << 16);
}

// async global->LDS, 16B per lane; LDS dest = wave-uniform base + lane*16
static __device__ __forceinline__ void gload16(const unsigned short* g,
                                               unsigned short* l) {
  __builtin_amdgcn_global_load_lds(
      (const __attribute__((address_space(1))) void*)g,
      (__attribute__((address_space(3))) void*)l, 16, 0, 0);
}

// ---------------------------------------------------------------------------
// Fused prep: ALL fp32 -> bf16 hi/lo splits + hi-only converts, one launch.
// ---------------------------------------------------------------------------
__global__ __launch_bounds__(256) void prep_all(
    const float* __restrict__ x1, unsigned short* __restrict__ x1h,
    unsigned short* __restrict__ x1l, const float* __restrict__ x2,
    unsigned short* __restrict__ x2h, unsigned short* __restrict__ x2l,
    const float* __restrict__ Wq, unsigned short* __restrict__ Wqh,
    unsigned short* __restrict__ Wql, const float* __restrict__ Wk,
    unsigned short* __restrict__ Wkh, unsigned short* __restrict__ Wkl,
    const float* __restrict__ Wv, unsigned short* __restrict__ Wvh,
    const float* __restrict__ Wo, unsigned short* __restrict__ Woh) {
  const int bi = blockIdx.x;
  const float* src;
  unsigned short *hi, *lo = nullptr;
  int lb;
  if (bi < 1536) {
    src = x1; hi = x1h; lo = x1l; lb = bi;
  } else if (bi < 7680) {
    src = x2; hi = x2h; lo = x2l; lb = bi - 1536;
  } else if (bi < 8256) {
    src = Wq; hi = Wqh; lo = Wql; lb = bi - 7680;
  } else if (bi < 8832) {
    src = Wk; hi = Wkh; lo = Wkl; lb = bi - 8256;
  } else if (bi < 9408) {
    src = Wv; hi = Wvh; lb = bi - 8832;
  } else {
    src = Wo; hi = Woh; lb = bi - 9408;
  }
  const int i = (lb * 256 + threadIdx.x) * 4;
  const float4 v = *(const float4*)&src[i];
  ushort4v h = {f2bf(v.x), f2bf(v.y), f2bf(v.z), f2bf(v.w)};
  *(ushort4v*)&hi[i] = h;
  if (lo) {
    ushort4v l = {f2bf(v.x - bf2f(h[0])), f2bf(v.y - bf2f(h[1])),
                  f2bf(v.z - bf2f(h[2])), f2bf(v.w - bf2f(h[3]))};
    *(ushort4v*)&lo[i] = l;
  }
}

// ---------------------------------------------------------------------------
// Core bf16 MFMA GEMM tile (unchanged from R7).
// ---------------------------------------------------------------------------
template <bool SPLIT, bool L2N, bool F32OUT>
static __device__ __forceinline__ void gemm_tile(
    const unsigned short* __restrict__ Ahg, const unsigned short* __restrict__ Alg,
    const unsigned short* __restrict__ Bhg, const unsigned short* __restrict__ Blg,
    void* __restrict__ Cv, int M, int N, int K, int m0, int n0,
    unsigned short* sAh, unsigned short* sBh, unsigned short* sAl,
    unsigned short* sBl) {
  const int tid = threadIdx.x;
  const int wave = tid >> 6;
  const int lane = tid & 63;
  const int wm = wave >> 1;
  const int wn = wave & 1;
  const int n15 = lane & 15;
  const int quad = lane >> 4;
  const int srow = lane >> 2;
  const int cpl = (lane & 3) ^ (srow >> 2);

  floatx4 acc[4][4];
#pragma unroll
  for (int i = 0; i < 4; ++i)
#pragma unroll
    for (int j = 0; j < 4; ++j) acc[i][j] = (floatx4){0.f, 0.f, 0.f, 0.f};

  for (int k0 = 0; k0 < K; k0 += 32) {
    __syncthreads();
#pragma unroll
    for (int jj = 0; jj < 2; ++jj) {
      const int j = wave * 2 + jj;
      const int row = j * 16 + srow;
      const size_t goffA = (size_t)(m0 + row) * K + k0 + cpl * 8;
      const size_t goffB = (size_t)(n0 + row) * K + k0 + cpl * 8;
      gload16(Ahg + goffA, &sAh[j * 512]);
      gload16(Bhg + goffB, &sBh[j * 512]);
      if constexpr (SPLIT) {
        gload16(Alg + goffA, &sAl[j * 512]);
        gload16(Blg + goffB, &sBl[j * 512]);
      }
    }
    __syncthreads();

    short8 afh[4], afl[4];
#pragma unroll
    for (int mt = 0; mt < 4; ++mt) {
      const int row = wm * 64 + mt * 16 + n15;
      const int off = row * 32 + ((quad ^ (n15 >> 2)) << 3);
      afh[mt] = *(const short8*)&sAh[off];
      if constexpr (SPLIT) afl[mt] = *(const short8*)&sAl[off];
    }
#pragma unroll
    for (int nt = 0; nt < 4; ++nt) {
      const int row = wn * 64 + nt * 16 + n15;
      const int off = row * 32 + ((quad ^ (n15 >> 2)) << 3);
      const short8 bfh = *(const short8*)&sBh[off];
      if constexpr (SPLIT) {
        const short8 bfl = *(const short8*)&sBl[off];
#pragma unroll
        for (int mt = 0; mt < 4; ++mt) {
          acc[mt][nt] = __builtin_amdgcn_mfma_f32_16x16x32_bf16(afh[mt], bfh, acc[mt][nt], 0, 0, 0);
          acc[mt][nt] = __builtin_amdgcn_mfma_f32_16x16x32_bf16(afh[mt], bfl, acc[mt][nt], 0, 0, 0);
          acc[mt][nt] = __builtin_amdgcn_mfma_f32_16x16x32_bf16(afl[mt], bfh, acc[mt][nt], 0, 0, 0);
        }
      } else {
#pragma unroll
        for (int mt = 0; mt < 4; ++mt)
          acc[mt][nt] = __builtin_amdgcn_mfma_f32_16x16x32_bf16(afh[mt], bfh, acc[mt][nt], 0, 0, 0);
      }
    }
  }

#pragma unroll
  for (int mt = 0; mt < 4; ++mt) {
    float scalev[4] = {1.f, 1.f, 1.f, 1.f};
    if constexpr (L2N) {
#pragma unroll
      for (int rr = 0; rr < 4; ++rr) {
        float ss = 0.f;
#pragma unroll
        for (int nt = 0; nt < 4; ++nt) ss += acc[mt][nt][rr] * acc[mt][nt][rr];
        ss += __shfl_xor(ss, 1, 64);
        ss += __shfl_xor(ss, 2, 64);
        ss += __shfl_xor(ss, 4, 64);
        ss += __shfl_xor(ss, 8, 64);
        scalev[rr] = 1.0f / fmaxf(sqrtf(ss), 1e-12f);
      }
    }
#pragma unroll
    for (int nt = 0; nt < 4; ++nt) {
#pragma unroll
      for (int rr = 0; rr < 4; ++rr) {
        const int row = m0 + wm * 64 + mt * 16 + quad * 4 + rr;
        const int col = n0 + wn * 64 + nt * 16 + n15;
        const float v = acc[mt][nt][rr] * scalev[rr];
        if constexpr (F32OUT)
          ((float*)Cv)[(size_t)row * N + col] = v;
        else
          ((unsigned short*)Cv)[(size_t)row * N + col] = f2bf(v);
      }
    }
  }
}

// ---------------------------------------------------------------------------
__global__ __launch_bounds__(256) void qk_proj(
    const unsigned short* __restrict__ x1h, const unsigned short* __restrict__ x1l,
    const unsigned short* __restrict__ Wqh, const unsigned short* __restrict__ Wql,
    const unsigned short* __restrict__ x2h, const unsigned short* __restrict__ x2l,
    const unsigned short* __restrict__ Wkh, const unsigned short* __restrict__ Wkl,
    unsigned short* __restrict__ qbf, unsigned short* __restrict__ kbf) {
  __shared__ __align__(16) unsigned short sAh[4096], sBh[4096], sAl[4096], sBl[4096];
  const int bi = blockIdx.x;
  if (bi < 96) {
    gemm_tile<true, true, false>(x1h, x1l, Wqh, Wql, qbf, B1, DMODEL, DMODEL,
                                 (bi / 6) * 128, (bi % 6) * 128, sAh, sBh, sAl, sBl);
  } else {
    const int b = bi - 96;
    gemm_tile<true, true, false>(x2h, x2l, Wkh, Wkl, kbf, B2, DMODEL, DMODEL,
                                 (b / 6) * 128, (b % 6) * 128, sAh, sBh, sAl, sBl);
  }
}

// ---------------------------------------------------------------------------
__global__ __launch_bounds__(256) void v_zero(
    const unsigned short* __restrict__ Wvh, const unsigned short* __restrict__ x2h,
    unsigned short* __restrict__ vtbf, float* __restrict__ aoacc,
    float* __restrict__ lacc) {
  __shared__ __align__(16) unsigned short sAh[4096], sBh[4096];
  const int bi = blockIdx.x;
  if (bi < 384) {
    gemm_tile<false, false, false>(Wvh, nullptr, x2h, nullptr, vtbf, DMODEL, B2,
                                   DMODEL, (bi / 64) * 128, (bi % 64) * 128,
                                   sAh, sBh, nullptr, nullptr);
  } else if (bi < 768) {
    const float4 z = {0.f, 0.f, 0.f, 0.f};
    float4* p = (float4*)aoacc + (size_t)(bi - 384) * 1024 + threadIdx.x;
    p[0] = z; p[256] = z; p[512] = z; p[768] = z;
  } else {
    const float4 z = {0.f, 0.f, 0.f, 0.f};
    float4* p = (float4*)lacc + (size_t)(bi - 768) * 1024 + threadIdx.x;
    p[0] = z; p[256] = z; p[512] = z; p[768] = z;
  }
}

// ---------------------------------------------------------------------------
// MFMA bf16 attention, 512-thread blocks (8 waves = 2 qsub x 4 ksub).
// Fixed softmax max = invt; partials additive. KC=128, KSPLIT=2, grid 768
// blocks -> 3 blocks/CU by LDS (51.2 KB), 24 waves/CU (75% occupancy).
// Each wave: 32q x 32k per chunk. Register-prefetch pipeline kept.
// S^T = K*Q^T (packed b64 P-stores), P round-trip via per-wave LDS.
// ---------------------------------------------------------------------------
#define KC 128
#define KSPLIT 2
#define NCH (B2 / KSPLIT / KC)  // 32
#define PSTR 36

__global__ __launch_bounds__(512, 6) void attn_mfma(
    const unsigned short* __restrict__ qb, const unsigned short* __restrict__ kb,
    const unsigned short* __restrict__ vt, float* __restrict__ aoacc,
    float* __restrict__ lacc, const int* __restrict__ invt_p) {
  __shared__ __align__(16) unsigned short smem[25600];  // 51200 B
  unsigned short* Kl = smem;            // [128 keys][64 d] swizzled, 16 KB
  unsigned short* Vl = smem + 8192;     // [64 d][128 keys] swizzled, 16 KB
  unsigned short* Psl = smem + 16384;   // 8 waves x [32 q][PSTR], 18432 B

  const float c2 = (float)invt_p[0] * 1.4426950408889634f;
  const int h = blockIdx.y;
  const int q0 = blockIdx.x * 64;
  const int tid = threadIdx.x;
  const int wave = tid >> 6;
  const int lane = tid & 63;
  const int qsub = wave >> 2;   // 0..1 : 32-query half
  const int ksub = wave & 3;    // 0..3 : 32-key quarter of the chunk
  const int n15 = lane & 15;
  const int quad = lane >> 4;
  const int kz0 = blockIdx.z * (B2 / KSPLIT);

  unsigned short* Ps = &Psl[wave * 32 * PSTR];

  short8 qf[2][2];
#pragma unroll
  for (int qt = 0; qt < 2; ++qt)
#pragma unroll
    for (int ks = 0; ks < 2; ++ks) {
      const int qrow = q0 + qsub * 32 + qt * 16 + n15;
      qf[qt][ks] = *(const short8*)&qb[(size_t)qrow * DMODEL + h * DH + ks * 32 + quad * 8];
    }

  floatx4 oacc[2][4];
#pragma unroll
  for (int qt = 0; qt < 2; ++qt)
#pragma unroll
    for (int nt = 0; nt < 4; ++nt) oacc[qt][nt] = (floatx4){0.f, 0.f, 0.f, 0.f};
  float lsum[2] = {0.f, 0.f};

  // staging: K = 1024 16B-slots, V = 1024 16B-slots; 512 threads x 2 each
  ushort8 kr[2], vr[2];
#pragma unroll
  for (int i = 0; i < 2; ++i) {
    const int s = i * 512 + tid;
    const int key = s >> 3, cpk = s & 7, chk = cpk ^ (key & 7);
    kr[i] = *(const ushort8*)&kb[(size_t)(kz0 + key) * DMODEL + h * DH + chk * 8];
    const int d = s >> 4, cpv = s & 15, chv = cpv ^ (d & 15);
    vr[i] = *(const ushort8*)&vt[(size_t)(h * DH + d) * B2 + kz0 + chv * 8];
  }

  for (int c = 0; c < NCH; ++c) {
    __syncthreads();
#pragma unroll
    for (int i = 0; i < 2; ++i) {
      const int s = i * 512 + tid;
      const int key = s >> 3, cpk = s & 7;
      *(ushort8*)&Kl[key * 64 + cpk * 8] = kr[i];
      const int d = s >> 4, cpv = s & 15;
      *(ushort8*)&Vl[d * 128 + cpv * 8] = vr[i];
    }
    if (c + 1 < NCH) {
      const int kc0n = kz0 + (c + 1) * KC;
#pragma unroll
      for (int i = 0; i < 2; ++i) {
        const int s = i * 512 + tid;
        const int key = s >> 3, cpk = s & 7, chk = cpk ^ (key & 7);
        kr[i] = *(const ushort8*)&kb[(size_t)(kc0n + key) * DMODEL + h * DH + chk * 8];
        const int d = s >> 4, cpv = s & 15, chv = cpv ^ (d & 15);
        vr[i] = *(const ushort8*)&vt[(size_t)(h * DH + d) * B2 + kc0n + chv * 8];
      }
    }
    __syncthreads();

    // S^T over this wave's 32 keys -> exp -> P
#pragma unroll
    for (int kt = 0; kt < 2; ++kt) {
      floatx4 s0 = {0.f, 0.f, 0.f, 0.f}, s1 = {0.f, 0.f, 0.f, 0.f};
#pragma unroll
      for (int ks = 0; ks < 2; ++ks) {
        const int key = ksub * 32 + kt * 16 + n15;
        const int cp = (ks * 4 + quad) ^ (n15 & 7);
        const short8 kf = *(const short8*)&Kl[key * 64 + cp * 8];
        s0 = __builtin_amdgcn_mfma_f32_16x16x32_bf16(kf, qf[0][ks], s0, 0, 0, 0);
        s1 = __builtin_amdgcn_mfma_f32_16x16x32_bf16(kf, qf[1][ks], s1, 0, 0, 0);
      }
      ushort4v p0, p1;
#pragma unroll
      for (int r = 0; r < 4; ++r) {
        const float e0 = exp2f(fmaf(s0[r], c2, -c2));
        const float e1 = exp2f(fmaf(s1[r], c2, -c2));
        lsum[0] += e0;
        lsum[1] += e1;
        p0[r] = f2bf(e0);
        p1[r] = f2bf(e1);
      }
      *(ushort4v*)&Ps[(0 * 16 + n15) * PSTR + kt * 16 + quad * 4] = p0;
      *(ushort4v*)&Ps[(1 * 16 + n15) * PSTR + kt * 16 + quad * 4] = p1;
    }
    // (no barrier: Ps wave-private)

    // O[32q x 64d] += P[32q x 32k] * V[32k x 64d]
    short8 pa[2];
#pragma unroll
    for (int qt = 0; qt < 2; ++qt)
      pa[qt] = *(const short8*)&Ps[(qt * 16 + n15) * PSTR + quad * 8];
#pragma unroll
    for (int nt = 0; nt < 4; ++nt) {
      const int dd = nt * 16 + n15;
      const int cp = (ksub * 4 + quad) ^ n15;
      const short8 vf = *(const short8*)&Vl[dd * 128 + cp * 8];
      oacc[0][nt] = __builtin_amdgcn_mfma_f32_16x16x32_bf16(pa[0], vf, oacc[0][nt], 0, 0, 0);
      oacc[1][nt] = __builtin_amdgcn_mfma_f32_16x16x32_bf16(pa[1], vf, oacc[1][nt], 0, 0, 0);
    }
  }

  // lsum: lane has partial for q = qt*16+n15 over wave's keys; reduce quads
#pragma unroll
  for (int qt = 0; qt < 2; ++qt) {
    float v = lsum[qt];
    v += __shfl_xor(v, 16, 64);
    v += __shfl_xor(v, 32, 64);
    lsum[qt] = v;
  }
  if (quad == 0) {
#pragma unroll
    for (int qt = 0; qt < 2; ++qt)
      atomicAdd(&lacc[(q0 + qsub * 32 + qt * 16 + n15) * NH + h], lsum[qt]);
  }

  // combine 4 ksub partials via LDS (alias smem: 3 x [64][64] f32 = 48 KB)
  __syncthreads();
  float* Osc = (float*)smem;
  if (ksub > 0) {
    float* buf = Osc + (ksub - 1) * 4096;
#pragma unroll
    for (int qt = 0; qt < 2; ++qt)
#pragma unroll
      for (int nt = 0; nt < 4; ++nt)
#pragma unroll
        for (int r = 0; r < 4; ++r) {
          const int row = qsub * 32 + qt * 16 + quad * 4 + r;
          buf[row * 64 + nt * 16 + n15] = oacc[qt][nt][r];
        }
  }
  __syncthreads();
  if (ksub == 0) {
#pragma unroll
    for (int qt = 0; qt < 2; ++qt)
#pragma unroll
      for (int nt = 0; nt < 4; ++nt)
#pragma unroll
        for (int r = 0; r < 4; ++r) {
          const int row = qsub * 32 + qt * 16 + quad * 4 + r;
          const int col = nt * 16 + n15;
          const float v = oacc[qt][nt][r] + Osc[row * 64 + col] +
                          Osc[4096 + row * 64 + col] + Osc[8192 + row * 64 + col];
          atomicAdd(&aoacc[(size_t)(q0 + row) * DMODEL + h * DH + col], v);
        }
  }
}

// ---------------------------------------------------------------------------
// Wo projection with fused ao-normalize A-staging (unchanged from R7).
// ---------------------------------------------------------------------------
__global__ __launch_bounds__(256) void wo_proj(
    const float* __restrict__ aoacc, const float* __restrict__ lacc,
    const unsigned short* __restrict__ Woh, float* __restrict__ woout) {
  __shared__ __align__(16) unsigned short sAh[4096], sBh[4096];
  const int bi = blockIdx.x;
  const int m0 = (bi / 6) * 128;
  const int n0 = (bi % 6) * 128;
  const int tid = threadIdx.x;
  const int wave = tid >> 6;
  const int lane = tid & 63;
  const int wm = wave >> 1;
  const int wn = wave & 1;
  const int n15 = lane & 15;
  const int quad = lane >> 4;
  const int srow = lane >> 2;
  const int cpl = (lane & 3) ^ (srow >> 2);

  floatx4 acc[4][4];
#pragma unroll
  for (int i = 0; i < 4; ++i)
#pragma unroll
    for (int j = 0; j < 4; ++j) acc[i][j] = (floatx4){0.f, 0.f, 0.f, 0.f};

  for (int k0 = 0; k0 < DMODEL; k0 += 32) {
    __syncthreads();
#pragma unroll
    for (int jj = 0; jj < 2; ++jj) {
      const int j = wave * 2 + jj;
      const int row = j * 16 + srow;
      const size_t ga = (size_t)(m0 + row) * DMODEL + k0 + cpl * 8;
      const float4 a0 = *(const float4*)&aoacc[ga];
      const float4 a1 = *(const float4*)&aoacc[ga + 4];
      const int head = (k0 + cpl * 8) >> 6;
      const float inv = 1.0f / lacc[(m0 + row) * NH + head];
      ushort8 ah = {f2bf(a0.x * inv), f2bf(a0.y * inv), f2bf(a0.z * inv),
                    f2bf(a0.w * inv), f2bf(a1.x * inv), f2bf(a1.y * inv),
                    f2bf(a1.z * inv), f2bf(a1.w * inv)};
      *(ushort8*)&sAh[j * 512 + lane * 8] = ah;
      gload16(Woh + (size_t)(n0 + row) * DMODEL + k0 + cpl * 8, &sBh[j * 512]);
    }
    __syncthreads();

    short8 afh[4];
#pragma unroll
    for (int mt = 0; mt < 4; ++mt) {
      const int row = wm * 64 + mt * 16 + n15;
      afh[mt] = *(const short8*)&sAh[row * 32 + ((quad ^ (n15 >> 2)) << 3)];
    }
#pragma unroll
    for (int nt = 0; nt < 4; ++nt) {
      const int row = wn * 64 + nt * 16 + n15;
      const short8 bfh = *(const short8*)&sBh[row * 32 + ((quad ^ (n15 >> 2)) << 3)];
#pragma unroll
      for (int mt = 0; mt < 4; ++mt)
        acc[mt][nt] = __builtin_amdgcn_mfma_f32_16x16x32_bf16(afh[mt], bfh, acc[mt][nt], 0, 0, 0);
    }
  }

#pragma unroll
  for (int mt = 0; mt < 4; ++mt)
#pragma unroll
    for (int nt = 0; nt < 4; ++nt)
#pragma unroll
      for (int rr = 0; rr < 4; ++rr) {
        const int row = m0 + wm * 64 + mt * 16 + quad * 4 + rr;
        const int col = n0 + wn * 64 + nt * 16 + n15;
        woout[(size_t)row * DMODEL + col] = acc[mt][nt][rr];
      }
}

// ---------------------------------------------------------------------------
__global__ __launch_bounds__(256) void l2norm_rows768_out(
    const float* __restrict__ x, float* __restrict__ out) {
  const int row = blockIdx.x;
  const float* xr = &x[(size_t)row * DMODEL];
  float ss = 0.0f;
  float vals[3];
#pragma unroll
  for (int i = 0; i < 3; ++i) {
    vals[i] = xr[threadIdx.x + i * 256];
    ss += vals[i] * vals[i];
  }
#pragma unroll
  for (int off = 32; off > 0; off >>= 1) ss += __shfl_xor(ss, off, 64);
  __shared__ float ws[4];
  if ((threadIdx.x & 63) == 0) ws[threadIdx.x >> 6] = ss;
  __syncthreads();
  const float tot = ws[0] + ws[1] + ws[2] + ws[3];
  const float sc = 1.0f / fmaxf(sqrtf(tot), 1e-12f);
  float* orow = &out[(size_t)row * DMODEL];
#pragma unroll
  for (int i = 0; i < 3; ++i) orow[threadIdx.x + i * 256] = vals[i] * sc;
}

// ---------------------------------------------------------------------------
extern "C" void kernel_launch(void* const* d_in, const int* in_sizes, int n_in,
                              void* d_out, int out_size, void* d_ws,
                              size_t ws_size, hipStream_t stream) {
  const float* x1 = (const float*)d_in[0];
  const float* x2 = (const float*)d_in[1];
  const float* Wq = (const float*)d_in[2];
  const float* Wk = (const float*)d_in[3];
  const float* Wv = (const float*)d_in[4];
  const float* Wo = (const float*)d_in[5];
  const int* invt = (const int*)d_in[6];
  float* outp = (float*)d_out;

  char* ws = (char*)d_ws;
  unsigned short* x1h = (unsigned short*)(ws + 0);
  unsigned short* x1l = (unsigned short*)(ws + 3145728);
  unsigned short* x2h = (unsigned short*)(ws + 6291456);
  unsigned short* x2l = (unsigned short*)(ws + 18874368);
  unsigned short* Wqh = (unsigned short*)(ws + 31457280);
  unsigned short* Wql = (unsigned short*)(ws + 32636928);
  unsigned short* Wkh = (unsigned short*)(ws + 33816576);
  unsigned short* Wkl = (unsigned short*)(ws + 34996224);
  unsigned short* Wvh = (unsigned short*)(ws + 36175872);
  unsigned short* Woh = (unsigned short*)(ws + 37355520);
  unsigned short* q_bf = (unsigned short*)(ws + 38535168);
  unsigned short* k_bf = (unsigned short*)(ws + 41680896);
  float* lacc = (float*)(ws + 54263808);
  float* aoacc = (float*)(ws + 0);
  unsigned short* vt_bf = (unsigned short*)(ws + 18874368);
  float* woout = (float*)(ws + 9437184);

  prep_all<<<9984, 256, 0, stream>>>(x1, x1h, x1l, x2, x2h, x2l, Wq, Wqh, Wql,
                                     Wk, Wkh, Wkl, Wv, Wvh, Wo, Woh);
  qk_proj<<<480, 256, 0, stream>>>(x1h, x1l, Wqh, Wql, x2h, x2l, Wkh, Wkl,
                                   q_bf, k_bf);
  v_zero<<<774, 256, 0, stream>>>(Wvh, x2h, vt_bf, aoacc, lacc);
  attn_mfma<<<dim3(B1 / 64, NH, KSPLIT), 512, 0, stream>>>(q_bf, k_bf, vt_bf,
                                                           aoacc, lacc, invt);
  wo_proj<<<96, 256, 0, stream>>>(aoacc, lacc, Woh, woout);
  l2norm_rows768_out<<<B1, 256, 0, stream>>>(woout, outp);
}

// Round 11
// 374.856 us; speedup vs baseline: 1.6871x; 1.6871x over previous
//
#include <hip/hip_runtime.h>
#include <hip/hip_bf16.h>
#include <math.h>

#define B1 2048
#define B2 8192
#define NH 12
#define DH 64
#define DMODEL 768

typedef __attribute__((ext_vector_type(8))) short short8;
typedef __attribute__((ext_vector_type(4))) float floatx4;
typedef __attribute__((ext_vector_type(8))) unsigned short ushort8;
typedef __attribute__((ext_vector_type(4))) unsigned short ushort4v;

static __device__ __forceinline__ unsigned short f2bf(float f) {
  __bf16 b = (__bf16)f;
  return __builtin_bit_cast(unsigned short, b);
}
static __device__ __forceinline__ float bf2f(unsigned short u) {
  return __builtin_bit_cast(float, ((unsigned)u) << 16);
}

// async global->LDS, 16B per lane; LDS dest = wave-uniform base + lane*16
static __device__ __forceinline__ void gload16(const unsigned short* g,
                                               unsigned short* l) {
  __builtin_amdgcn_global_load_lds(
      (const __attribute__((address_space(1))) void*)g,
      (__attribute__((address_space(3))) void*)l, 16, 0, 0);
}

// ---------------------------------------------------------------------------
// Fused prep: ALL fp32 -> bf16 hi/lo splits + hi-only converts, one launch.
// ---------------------------------------------------------------------------
__global__ __launch_bounds__(256) void prep_all(
    const float* __restrict__ x1, unsigned short* __restrict__ x1h,
    unsigned short* __restrict__ x1l, const float* __restrict__ x2,
    unsigned short* __restrict__ x2h, unsigned short* __restrict__ x2l,
    const float* __restrict__ Wq, unsigned short* __restrict__ Wqh,
    unsigned short* __restrict__ Wql, const float* __restrict__ Wk,
    unsigned short* __restrict__ Wkh, unsigned short* __restrict__ Wkl,
    const float* __restrict__ Wv, unsigned short* __restrict__ Wvh,
    const float* __restrict__ Wo, unsigned short* __restrict__ Woh) {
  const int bi = blockIdx.x;
  const float* src;
  unsigned short *hi, *lo = nullptr;
  int lb;
  if (bi < 1536) {
    src = x1; hi = x1h; lo = x1l; lb = bi;
  } else if (bi < 7680) {
    src = x2; hi = x2h; lo = x2l; lb = bi - 1536;
  } else if (bi < 8256) {
    src = Wq; hi = Wqh; lo = Wql; lb = bi - 7680;
  } else if (bi < 8832) {
    src = Wk; hi = Wkh; lo = Wkl; lb = bi - 8256;
  } else if (bi < 9408) {
    src = Wv; hi = Wvh; lb = bi - 8832;
  } else {
    src = Wo; hi = Woh; lb = bi - 9408;
  }
  const int i = (lb * 256 + threadIdx.x) * 4;
  const float4 v = *(const float4*)&src[i];
  ushort4v h = {f2bf(v.x), f2bf(v.y), f2bf(v.z), f2bf(v.w)};
  *(ushort4v*)&hi[i] = h;
  if (lo) {
    ushort4v l = {f2bf(v.x - bf2f(h[0])), f2bf(v.y - bf2f(h[1])),
                  f2bf(v.z - bf2f(h[2])), f2bf(v.w - bf2f(h[3]))};
    *(ushort4v*)&lo[i] = l;
  }
}

// ---------------------------------------------------------------------------
// Core bf16 MFMA GEMM tile (unchanged from R7, which passed).
// ---------------------------------------------------------------------------
template <bool SPLIT, bool L2N, bool F32OUT>
static __device__ __forceinline__ void gemm_tile(
    const unsigned short* __restrict__ Ahg, const unsigned short* __restrict__ Alg,
    const unsigned short* __restrict__ Bhg, const unsigned short* __restrict__ Blg,
    void* __restrict__ Cv, int M, int N, int K, int m0, int n0,
    unsigned short* sAh, unsigned short* sBh, unsigned short* sAl,
    unsigned short* sBl) {
  const int tid = threadIdx.x;
  const int wave = tid >> 6;
  const int lane = tid & 63;
  const int wm = wave >> 1;
  const int wn = wave & 1;
  const int n15 = lane & 15;
  const int quad = lane >> 4;
  const int srow = lane >> 2;
  const int cpl = (lane & 3) ^ (srow >> 2);

  floatx4 acc[4][4];
#pragma unroll
  for (int i = 0; i < 4; ++i)
#pragma unroll
    for (int j = 0; j < 4; ++j) acc[i][j] = (floatx4){0.f, 0.f, 0.f, 0.f};

  for (int k0 = 0; k0 < K; k0 += 32) {
    __syncthreads();
#pragma unroll
    for (int jj = 0; jj < 2; ++jj) {
      const int j = wave * 2 + jj;
      const int row = j * 16 + srow;
      const size_t goffA = (size_t)(m0 + row) * K + k0 + cpl * 8;
      const size_t goffB = (size_t)(n0 + row) * K + k0 + cpl * 8;
      gload16(Ahg + goffA, &sAh[j * 512]);
      gload16(Bhg + goffB, &sBh[j * 512]);
      if constexpr (SPLIT) {
        gload16(Alg + goffA, &sAl[j * 512]);
        gload16(Blg + goffB, &sBl[j * 512]);
      }
    }
    __syncthreads();

    short8 afh[4], afl[4];
#pragma unroll
    for (int mt = 0; mt < 4; ++mt) {
      const int row = wm * 64 + mt * 16 + n15;
      const int off = row * 32 + ((quad ^ (n15 >> 2)) << 3);
      afh[mt] = *(const short8*)&sAh[off];
      if constexpr (SPLIT) afl[mt] = *(const short8*)&sAl[off];
    }
#pragma unroll
    for (int nt = 0; nt < 4; ++nt) {
      const int row = wn * 64 + nt * 16 + n15;
      const int off = row * 32 + ((quad ^ (n15 >> 2)) << 3);
      const short8 bfh = *(const short8*)&sBh[off];
      if constexpr (SPLIT) {
        const short8 bfl = *(const short8*)&sBl[off];
#pragma unroll
        for (int mt = 0; mt < 4; ++mt) {
          acc[mt][nt] = __builtin_amdgcn_mfma_f32_16x16x32_bf16(afh[mt], bfh, acc[mt][nt], 0, 0, 0);
          acc[mt][nt] = __builtin_amdgcn_mfma_f32_16x16x32_bf16(afh[mt], bfl, acc[mt][nt], 0, 0, 0);
          acc[mt][nt] = __builtin_amdgcn_mfma_f32_16x16x32_bf16(afl[mt], bfh, acc[mt][nt], 0, 0, 0);
        }
      } else {
#pragma unroll
        for (int mt = 0; mt < 4; ++mt)
          acc[mt][nt] = __builtin_amdgcn_mfma_f32_16x16x32_bf16(afh[mt], bfh, acc[mt][nt], 0, 0, 0);
      }
    }
  }

#pragma unroll
  for (int mt = 0; mt < 4; ++mt) {
    float scalev[4] = {1.f, 1.f, 1.f, 1.f};
    if constexpr (L2N) {
#pragma unroll
      for (int rr = 0; rr < 4; ++rr) {
        float ss = 0.f;
#pragma unroll
        for (int nt = 0; nt < 4; ++nt) ss += acc[mt][nt][rr] * acc[mt][nt][rr];
        ss += __shfl_xor(ss, 1, 64);
        ss += __shfl_xor(ss, 2, 64);
        ss += __shfl_xor(ss, 4, 64);
        ss += __shfl_xor(ss, 8, 64);
        scalev[rr] = 1.0f / fmaxf(sqrtf(ss), 1e-12f);
      }
    }
#pragma unroll
    for (int nt = 0; nt < 4; ++nt) {
#pragma unroll
      for (int rr = 0; rr < 4; ++rr) {
        const int row = m0 + wm * 64 + mt * 16 + quad * 4 + rr;
        const int col = n0 + wn * 64 + nt * 16 + n15;
        const float v = acc[mt][nt][rr] * scalev[rr];
        if constexpr (F32OUT)
          ((float*)Cv)[(size_t)row * N + col] = v;
        else
          ((unsigned short*)Cv)[(size_t)row * N + col] = f2bf(v);
      }
    }
  }
}

// ---------------------------------------------------------------------------
// q-proj + k-proj fused. MUST be a separate launch from v_zero: v_zero writes
// regions (aoacc = x1 region, vt_bf = x2l region) that this kernel READS.
// ---------------------------------------------------------------------------
__global__ __launch_bounds__(256) void qk_proj(
    const unsigned short* __restrict__ x1h, const unsigned short* __restrict__ x1l,
    const unsigned short* __restrict__ Wqh, const unsigned short* __restrict__ Wql,
    const unsigned short* __restrict__ x2h, const unsigned short* __restrict__ x2l,
    const unsigned short* __restrict__ Wkh, const unsigned short* __restrict__ Wkl,
    unsigned short* __restrict__ qbf, unsigned short* __restrict__ kbf) {
  __shared__ __align__(16) unsigned short sAh[4096], sBh[4096], sAl[4096], sBl[4096];
  const int bi = blockIdx.x;
  if (bi < 96) {
    gemm_tile<true, true, false>(x1h, x1l, Wqh, Wql, qbf, B1, DMODEL, DMODEL,
                                 (bi / 6) * 128, (bi % 6) * 128, sAh, sBh, sAl, sBl);
  } else {
    const int b = bi - 96;
    gemm_tile<true, true, false>(x2h, x2l, Wkh, Wkl, kbf, B2, DMODEL, DMODEL,
                                 (b / 6) * 128, (b % 6) * 128, sAh, sBh, sAl, sBl);
  }
}

// ---------------------------------------------------------------------------
// v-proj (vt = Wv @ x2^T) + zero aoacc + zero lacc. Safe to fuse: reads x2h
// (live), writes x2l/x1 regions (dead after qk_proj).
// ---------------------------------------------------------------------------
__global__ __launch_bounds__(256) void v_zero(
    const unsigned short* __restrict__ Wvh, const unsigned short* __restrict__ x2h,
    unsigned short* __restrict__ vtbf, float* __restrict__ aoacc,
    float* __restrict__ lacc) {
  __shared__ __align__(16) unsigned short sAh[4096], sBh[4096];
  const int bi = blockIdx.x;
  if (bi < 384) {
    gemm_tile<false, false, false>(Wvh, nullptr, x2h, nullptr, vtbf, DMODEL, B2,
                                   DMODEL, (bi / 64) * 128, (bi % 64) * 128,
                                   sAh, sBh, nullptr, nullptr);
  } else if (bi < 768) {
    const float4 z = {0.f, 0.f, 0.f, 0.f};
    float4* p = (float4*)aoacc + (size_t)(bi - 384) * 1024 + threadIdx.x;
    p[0] = z; p[256] = z; p[512] = z; p[768] = z;
  } else {
    const float4 z = {0.f, 0.f, 0.f, 0.f};
    float4* p = (float4*)lacc + (size_t)(bi - 768) * 1024 + threadIdx.x;
    p[0] = z; p[256] = z; p[512] = z; p[768] = z;
  }
}

// ---------------------------------------------------------------------------
// MFMA bf16 attention: 256 threads (2 qsub x 2 ksub), KC=64, KSPLIT=2.
// LDS 25600 B (Kl 8192 + Vl 8192 + Psl 9216) -> 6 blocks/CU.
// __launch_bounds__(256,5): VGPR cap ~102, body ~70 -> no spill cliff.
// ---------------------------------------------------------------------------
#define KC 64
#define KSPLIT 2
#define NCH (B2 / KSPLIT / KC)  // 64
#define PSTR 36

__global__ __launch_bounds__(256, 5) void attn_mfma(
    const unsigned short* __restrict__ qb, const unsigned short* __restrict__ kb,
    const unsigned short* __restrict__ vt, float* __restrict__ aoacc,
    float* __restrict__ lacc, const int* __restrict__ invt_p) {
  __shared__ __align__(16) unsigned short smem[12800];  // 25600 B exact
  unsigned short* Kl = smem;            // [64 keys][64 d] swizzled
  unsigned short* Vl = smem + 4096;     // [64 d][64 keys] swizzled
  unsigned short* Psl = smem + 8192;    // 4 waves x [32 q][PSTR] = 4608

  const float c2 = (float)invt_p[0] * 1.4426950408889634f;
  const int h = blockIdx.y;
  const int q0 = blockIdx.x * 64;
  const int tid = threadIdx.x;
  const int wave = tid >> 6;
  const int lane = tid & 63;
  const int qsub = wave >> 1;
  const int ksub = wave & 1;
  const int n15 = lane & 15;
  const int quad = lane >> 4;
  const int kz0 = blockIdx.z * (B2 / KSPLIT);

  unsigned short* Ps = &Psl[wave * 32 * PSTR];

  short8 qf[2][2];
#pragma unroll
  for (int qt = 0; qt < 2; ++qt)
#pragma unroll
    for (int ks = 0; ks < 2; ++ks) {
      const int qrow = q0 + qsub * 32 + qt * 16 + n15;
      qf[qt][ks] = *(const short8*)&qb[(size_t)qrow * DMODEL + h * DH + ks * 32 + quad * 8];
    }

  floatx4 oacc[2][4];
#pragma unroll
  for (int qt = 0; qt < 2; ++qt)
#pragma unroll
    for (int nt = 0; nt < 4; ++nt) oacc[qt][nt] = (floatx4){0.f, 0.f, 0.f, 0.f};
  float lsum[2] = {0.f, 0.f};

  ushort8 kr[2], vr[2];
#pragma unroll
  for (int i = 0; i < 2; ++i) {
    const int s = i * 256 + tid;
    const int key = s >> 3, cpk = s & 7, chk = cpk ^ (key & 7);
    kr[i] = *(const ushort8*)&kb[(size_t)(kz0 + key) * DMODEL + h * DH + chk * 8];
    vr[i] = *(const ushort8*)&vt[(size_t)(h * DH + key) * B2 + kz0 + chk * 8];
  }

  for (int c = 0; c < NCH; ++c) {
    __syncthreads();
#pragma unroll
    for (int i = 0; i < 2; ++i) {
      const int s = i * 256 + tid;
      const int key = s >> 3, cpk = s & 7;
      *(ushort8*)&Kl[key * 64 + cpk * 8] = kr[i];
      *(ushort8*)&Vl[key * 64 + cpk * 8] = vr[i];
    }
    if (c + 1 < NCH) {
      const int kc0n = kz0 + (c + 1) * KC;
#pragma unroll
      for (int i = 0; i < 2; ++i) {
        const int s = i * 256 + tid;
        const int key = s >> 3, cpk = s & 7, chk = cpk ^ (key & 7);
        kr[i] = *(const ushort8*)&kb[(size_t)(kc0n + key) * DMODEL + h * DH + chk * 8];
        vr[i] = *(const ushort8*)&vt[(size_t)(h * DH + key) * B2 + kc0n + chk * 8];
      }
    }
    __syncthreads();

#pragma unroll
    for (int kt = 0; kt < 2; ++kt) {
      floatx4 s0 = {0.f, 0.f, 0.f, 0.f}, s1 = {0.f, 0.f, 0.f, 0.f};
#pragma unroll
      for (int ks = 0; ks < 2; ++ks) {
        const int key = ksub * 32 + kt * 16 + n15;
        const int cp = (ks * 4 + quad) ^ (n15 & 7);
        const short8 kf = *(const short8*)&Kl[key * 64 + cp * 8];
        s0 = __builtin_amdgcn_mfma_f32_16x16x32_bf16(kf, qf[0][ks], s0, 0, 0, 0);
        s1 = __builtin_amdgcn_mfma_f32_16x16x32_bf16(kf, qf[1][ks], s1, 0, 0, 0);
      }
      ushort4v p0, p1;
#pragma unroll
      for (int r = 0; r < 4; ++r) {
        const float e0 = exp2f(fmaf(s0[r], c2, -c2));
        const float e1 = exp2f(fmaf(s1[r], c2, -c2));
        lsum[0] += e0;
        lsum[1] += e1;
        p0[r] = f2bf(e0);
        p1[r] = f2bf(e1);
      }
      *(ushort4v*)&Ps[(0 * 16 + n15) * PSTR + kt * 16 + quad * 4] = p0;
      *(ushort4v*)&Ps[(1 * 16 + n15) * PSTR + kt * 16 + quad * 4] = p1;
    }

    short8 pa[2];
#pragma unroll
    for (int qt = 0; qt < 2; ++qt)
      pa[qt] = *(const short8*)&Ps[(qt * 16 + n15) * PSTR + quad * 8];
#pragma unroll
    for (int nt = 0; nt < 4; ++nt) {
      const int dd = nt * 16 + n15;
      const int cp = (ksub * 4 + quad) ^ (n15 & 7);
      const short8 vf = *(const short8*)&Vl[dd * 64 + cp * 8];
      oacc[0][nt] = __builtin_amdgcn_mfma_f32_16x16x32_bf16(pa[0], vf, oacc[0][nt], 0, 0, 0);
      oacc[1][nt] = __builtin_amdgcn_mfma_f32_16x16x32_bf16(pa[1], vf, oacc[1][nt], 0, 0, 0);
    }
  }

#pragma unroll
  for (int qt = 0; qt < 2; ++qt) {
    float v = lsum[qt];
    v += __shfl_xor(v, 16, 64);
    v += __shfl_xor(v, 32, 64);
    lsum[qt] = v;
  }
  if (quad == 0) {
#pragma unroll
    for (int qt = 0; qt < 2; ++qt)
      atomicAdd(&lacc[(q0 + qsub * 32 + qt * 16 + n15) * NH + h], lsum[qt]);
  }

  __syncthreads();
  float* Osc = (float*)smem;
  if (ksub == 1) {
#pragma unroll
    for (int qt = 0; qt < 2; ++qt)
#pragma unroll
      for (int nt = 0; nt < 4; ++nt)
#pragma unroll
        for (int r = 0; r < 4; ++r) {
          const int row = qsub * 32 + qt * 16 + quad * 4 + r;
          Osc[row * 64 + nt * 16 + n15] = oacc[qt][nt][r];
        }
  }
  __syncthreads();
  if (ksub == 0) {
#pragma unroll
    for (int qt = 0; qt < 2; ++qt)
#pragma unroll
      for (int nt = 0; nt < 4; ++nt)
#pragma unroll
        for (int r = 0; r < 4; ++r) {
          const int row = qsub * 32 + qt * 16 + quad * 4 + r;
          const float v = oacc[qt][nt][r] + Osc[row * 64 + nt * 16 + n15];
          atomicAdd(&aoacc[(size_t)(q0 + row) * DMODEL + h * DH + nt * 16 + n15], v);
        }
  }
}

// ---------------------------------------------------------------------------
// Wo projection with fused ao-normalize A-staging (unchanged from R7).
// ---------------------------------------------------------------------------
__global__ __launch_bounds__(256) void wo_proj(
    const float* __restrict__ aoacc, const float* __restrict__ lacc,
    const unsigned short* __restrict__ Woh, float* __restrict__ woout) {
  __shared__ __align__(16) unsigned short sAh[4096], sBh[4096];
  const int bi = blockIdx.x;
  const int m0 = (bi / 6) * 128;
  const int n0 = (bi % 6) * 128;
  const int tid = threadIdx.x;
  const int wave = tid >> 6;
  const int lane = tid & 63;
  const int wm = wave >> 1;
  const int wn = wave & 1;
  const int n15 = lane & 15;
  const int quad = lane >> 4;
  const int srow = lane >> 2;
  const int cpl = (lane & 3) ^ (srow >> 2);

  floatx4 acc[4][4];
#pragma unroll
  for (int i = 0; i < 4; ++i)
#pragma unroll
    for (int j = 0; j < 4; ++j) acc[i][j] = (floatx4){0.f, 0.f, 0.f, 0.f};

  for (int k0 = 0; k0 < DMODEL; k0 += 32) {
    __syncthreads();
#pragma unroll
    for (int jj = 0; jj < 2; ++jj) {
      const int j = wave * 2 + jj;
      const int row = j * 16 + srow;
      const size_t ga = (size_t)(m0 + row) * DMODEL + k0 + cpl * 8;
      const float4 a0 = *(const float4*)&aoacc[ga];
      const float4 a1 = *(const float4*)&aoacc[ga + 4];
      const int head = (k0 + cpl * 8) >> 6;
      const float inv = 1.0f / lacc[(m0 + row) * NH + head];
      ushort8 ah = {f2bf(a0.x * inv), f2bf(a0.y * inv), f2bf(a0.z * inv),
                    f2bf(a0.w * inv), f2bf(a1.x * inv), f2bf(a1.y * inv),
                    f2bf(a1.z * inv), f2bf(a1.w * inv)};
      *(ushort8*)&sAh[j * 512 + lane * 8] = ah;
      gload16(Woh + (size_t)(n0 + row) * DMODEL + k0 + cpl * 8, &sBh[j * 512]);
    }
    __syncthreads();

    short8 afh[4];
#pragma unroll
    for (int mt = 0; mt < 4; ++mt) {
      const int row = wm * 64 + mt * 16 + n15;
      afh[mt] = *(const short8*)&sAh[row * 32 + ((quad ^ (n15 >> 2)) << 3)];
    }
#pragma unroll
    for (int nt = 0; nt < 4; ++nt) {
      const int row = wn * 64 + nt * 16 + n15;
      const short8 bfh = *(const short8*)&sBh[row * 32 + ((quad ^ (n15 >> 2)) << 3)];
#pragma unroll
      for (int mt = 0; mt < 4; ++mt)
        acc[mt][nt] = __builtin_amdgcn_mfma_f32_16x16x32_bf16(afh[mt], bfh, acc[mt][nt], 0, 0, 0);
    }
  }

#pragma unroll
  for (int mt = 0; mt < 4; ++mt)
#pragma unroll
    for (int nt = 0; nt < 4; ++nt)
#pragma unroll
      for (int rr = 0; rr < 4; ++rr) {
        const int row = m0 + wm * 64 + mt * 16 + quad * 4 + rr;
        const int col = n0 + wn * 64 + nt * 16 + n15;
        woout[(size_t)row * DMODEL + col] = acc[mt][nt][rr];
      }
}

// ---------------------------------------------------------------------------
__global__ __launch_bounds__(256) void l2norm_rows768_out(
    const float* __restrict__ x, float* __restrict__ out) {
  const int row = blockIdx.x;
  const float* xr = &x[(size_t)row * DMODEL];
  float ss = 0.0f;
  float vals[3];
#pragma unroll
  for (int i = 0; i < 3; ++i) {
    vals[i] = xr[threadIdx.x + i * 256];
    ss += vals[i] * vals[i];
  }
#pragma unroll
  for (int off = 32; off > 0; off >>= 1) ss += __shfl_xor(ss, off, 64);
  __shared__ float ws[4];
  if ((threadIdx.x & 63) == 0) ws[threadIdx.x >> 6] = ss;
  __syncthreads();
  const float tot = ws[0] + ws[1] + ws[2] + ws[3];
  const float sc = 1.0f / fmaxf(sqrtf(tot), 1e-12f);
  float* orow = &out[(size_t)row * DMODEL];
#pragma unroll
  for (int i = 0; i < 3; ++i) orow[threadIdx.x + i * 256] = vals[i] * sc;
}

// ---------------------------------------------------------------------------
extern "C" void kernel_launch(void* const* d_in, const int* in_sizes, int n_in,
                              void* d_out, int out_size, void* d_ws,
                              size_t ws_size, hipStream_t stream) {
  const float* x1 = (const float*)d_in[0];
  const float* x2 = (const float*)d_in[1];
  const float* Wq = (const float*)d_in[2];
  const float* Wk = (const float*)d_in[3];
  const float* Wv = (const float*)d_in[4];
  const float* Wo = (const float*)d_in[5];
  const int* invt = (const int*)d_in[6];
  float* outp = (float*)d_out;

  // Aliases cross LAUNCH boundaries only (G16: no intra-launch ordering):
  //  aoacc (x1 region) & vt_bf (x2l region) written in v_zero, AFTER qk_proj
  //  has consumed x1h/x1l/x2l. woout (x2h region) written in wo_proj, after
  //  v_zero consumed x2h.
  char* ws = (char*)d_ws;
  unsigned short* x1h = (unsigned short*)(ws + 0);
  unsigned short* x1l = (unsigned short*)(ws + 3145728);
  unsigned short* x2h = (unsigned short*)(ws + 6291456);
  unsigned short* x2l = (unsigned short*)(ws + 18874368);
  unsigned short* Wqh = (unsigned short*)(ws + 31457280);
  unsigned short* Wql = (unsigned short*)(ws + 32636928);
  unsigned short* Wkh = (unsigned short*)(ws + 33816576);
  unsigned short* Wkl = (unsigned short*)(ws + 34996224);
  unsigned short* Wvh = (unsigned short*)(ws + 36175872);
  unsigned short* Woh = (unsigned short*)(ws + 37355520);
  unsigned short* q_bf = (unsigned short*)(ws + 38535168);
  unsigned short* k_bf = (unsigned short*)(ws + 41680896);
  float* lacc = (float*)(ws + 54263808);
  float* aoacc = (float*)(ws + 0);
  unsigned short* vt_bf = (unsigned short*)(ws + 18874368);
  float* woout = (float*)(ws + 9437184);

  prep_all<<<9984, 256, 0, stream>>>(x1, x1h, x1l, x2, x2h, x2l, Wq, Wqh, Wql,
                                     Wk, Wkh, Wkl, Wv, Wvh, Wo, Woh);
  qk_proj<<<480, 256, 0, stream>>>(x1h, x1l, Wqh, Wql, x2h, x2l, Wkh, Wkl,
                                   q_bf, k_bf);
  v_zero<<<774, 256, 0, stream>>>(Wvh, x2h, vt_bf, aoacc, lacc);
  attn_mfma<<<dim3(B1 / 64, NH, KSPLIT), 256, 0, stream>>>(q_bf, k_bf, vt_bf,
                                                           aoacc, lacc, invt);
  wo_proj<<<96, 256, 0, stream>>>(aoacc, lacc, Woh, woout);
  l2norm_rows768_out<<<B1, 256, 0, stream>>>(woout, outp);
}

// Round 12
// 311.460 us; speedup vs baseline: 2.0306x; 1.2035x over previous
//
#include <hip/hip_runtime.h>
#include <hip/hip_bf16.h>
#include <math.h>

#define B1 2048
#define B2 8192
#define NH 12
#define DH 64
#define DMODEL 768

typedef __attribute__((ext_vector_type(8))) short short8;
typedef __attribute__((ext_vector_type(4))) float floatx4;
typedef __attribute__((ext_vector_type(8))) unsigned short ushort8;
typedef __attribute__((ext_vector_type(4))) unsigned short ushort4v;

static __device__ __forceinline__ unsigned short f2bf(float f) {
  __bf16 b = (__bf16)f;
  return __builtin_bit_cast(unsigned short, b);
}
static __device__ __forceinline__ float bf2f(unsigned short u) {
  return __builtin_bit_cast(float, ((unsigned)u) << 16);
}

// async global->LDS, 16B per lane; LDS dest = wave-uniform base + lane*16
static __device__ __forceinline__ void gload16(const unsigned short* g,
                                               unsigned short* l) {
  __builtin_amdgcn_global_load_lds(
      (const __attribute__((address_space(1))) void*)g,
      (__attribute__((address_space(3))) void*)l, 16, 0, 0);
}

// ---------------------------------------------------------------------------
// Fused prep: ALL fp32 -> bf16 hi/lo splits + hi-only converts, one launch.
// ---------------------------------------------------------------------------
__global__ __launch_bounds__(256) void prep_all(
    const float* __restrict__ x1, unsigned short* __restrict__ x1h,
    unsigned short* __restrict__ x1l, const float* __restrict__ x2,
    unsigned short* __restrict__ x2h, unsigned short* __restrict__ x2l,
    const float* __restrict__ Wq, unsigned short* __restrict__ Wqh,
    unsigned short* __restrict__ Wql, const float* __restrict__ Wk,
    unsigned short* __restrict__ Wkh, unsigned short* __restrict__ Wkl,
    const float* __restrict__ Wv, unsigned short* __restrict__ Wvh,
    const float* __restrict__ Wo, unsigned short* __restrict__ Woh) {
  const int bi = blockIdx.x;
  const float* src;
  unsigned short *hi, *lo = nullptr;
  int lb;
  if (bi < 1536) {
    src = x1; hi = x1h; lo = x1l; lb = bi;
  } else if (bi < 7680) {
    src = x2; hi = x2h; lo = x2l; lb = bi - 1536;
  } else if (bi < 8256) {
    src = Wq; hi = Wqh; lo = Wql; lb = bi - 7680;
  } else if (bi < 8832) {
    src = Wk; hi = Wkh; lo = Wkl; lb = bi - 8256;
  } else if (bi < 9408) {
    src = Wv; hi = Wvh; lb = bi - 8832;
  } else {
    src = Wo; hi = Woh; lb = bi - 9408;
  }
  const int i = (lb * 256 + threadIdx.x) * 4;
  const float4 v = *(const float4*)&src[i];
  ushort4v h = {f2bf(v.x), f2bf(v.y), f2bf(v.z), f2bf(v.w)};
  *(ushort4v*)&hi[i] = h;
  if (lo) {
    ushort4v l = {f2bf(v.x - bf2f(h[0])), f2bf(v.y - bf2f(h[1])),
                  f2bf(v.z - bf2f(h[2])), f2bf(v.w - bf2f(h[3]))};
    *(ushort4v*)&lo[i] = l;
  }
}

// ---------------------------------------------------------------------------
// Core bf16 MFMA GEMM tile (unchanged from R7, which passed).
// ---------------------------------------------------------------------------
template <bool SPLIT, bool L2N, bool F32OUT>
static __device__ __forceinline__ void gemm_tile(
    const unsigned short* __restrict__ Ahg, const unsigned short* __restrict__ Alg,
    const unsigned short* __restrict__ Bhg, const unsigned short* __restrict__ Blg,
    void* __restrict__ Cv, int M, int N, int K, int m0, int n0,
    unsigned short* sAh, unsigned short* sBh, unsigned short* sAl,
    unsigned short* sBl) {
  const int tid = threadIdx.x;
  const int wave = tid >> 6;
  const int lane = tid & 63;
  const int wm = wave >> 1;
  const int wn = wave & 1;
  const int n15 = lane & 15;
  const int quad = lane >> 4;
  const int srow = lane >> 2;
  const int cpl = (lane & 3) ^ (srow >> 2);

  floatx4 acc[4][4];
#pragma unroll
  for (int i = 0; i < 4; ++i)
#pragma unroll
    for (int j = 0; j < 4; ++j) acc[i][j] = (floatx4){0.f, 0.f, 0.f, 0.f};

  for (int k0 = 0; k0 < K; k0 += 32) {
    __syncthreads();
#pragma unroll
    for (int jj = 0; jj < 2; ++jj) {
      const int j = wave * 2 + jj;
      const int row = j * 16 + srow;
      const size_t goffA = (size_t)(m0 + row) * K + k0 + cpl * 8;
      const size_t goffB = (size_t)(n0 + row) * K + k0 + cpl * 8;
      gload16(Ahg + goffA, &sAh[j * 512]);
      gload16(Bhg + goffB, &sBh[j * 512]);
      if constexpr (SPLIT) {
        gload16(Alg + goffA, &sAl[j * 512]);
        gload16(Blg + goffB, &sBl[j * 512]);
      }
    }
    __syncthreads();

    short8 afh[4], afl[4];
#pragma unroll
    for (int mt = 0; mt < 4; ++mt) {
      const int row = wm * 64 + mt * 16 + n15;
      const int off = row * 32 + ((quad ^ (n15 >> 2)) << 3);
      afh[mt] = *(const short8*)&sAh[off];
      if constexpr (SPLIT) afl[mt] = *(const short8*)&sAl[off];
    }
#pragma unroll
    for (int nt = 0; nt < 4; ++nt) {
      const int row = wn * 64 + nt * 16 + n15;
      const int off = row * 32 + ((quad ^ (n15 >> 2)) << 3);
      const short8 bfh = *(const short8*)&sBh[off];
      if constexpr (SPLIT) {
        const short8 bfl = *(const short8*)&sBl[off];
#pragma unroll
        for (int mt = 0; mt < 4; ++mt) {
          acc[mt][nt] = __builtin_amdgcn_mfma_f32_16x16x32_bf16(afh[mt], bfh, acc[mt][nt], 0, 0, 0);
          acc[mt][nt] = __builtin_amdgcn_mfma_f32_16x16x32_bf16(afh[mt], bfl, acc[mt][nt], 0, 0, 0);
          acc[mt][nt] = __builtin_amdgcn_mfma_f32_16x16x32_bf16(afl[mt], bfh, acc[mt][nt], 0, 0, 0);
        }
      } else {
#pragma unroll
        for (int mt = 0; mt < 4; ++mt)
          acc[mt][nt] = __builtin_amdgcn_mfma_f32_16x16x32_bf16(afh[mt], bfh, acc[mt][nt], 0, 0, 0);
      }
    }
  }

#pragma unroll
  for (int mt = 0; mt < 4; ++mt) {
    float scalev[4] = {1.f, 1.f, 1.f, 1.f};
    if constexpr (L2N) {
#pragma unroll
      for (int rr = 0; rr < 4; ++rr) {
        float ss = 0.f;
#pragma unroll
        for (int nt = 0; nt < 4; ++nt) ss += acc[mt][nt][rr] * acc[mt][nt][rr];
        ss += __shfl_xor(ss, 1, 64);
        ss += __shfl_xor(ss, 2, 64);
        ss += __shfl_xor(ss, 4, 64);
        ss += __shfl_xor(ss, 8, 64);
        scalev[rr] = 1.0f / fmaxf(sqrtf(ss), 1e-12f);
      }
    }
#pragma unroll
    for (int nt = 0; nt < 4; ++nt) {
#pragma unroll
      for (int rr = 0; rr < 4; ++rr) {
        const int row = m0 + wm * 64 + mt * 16 + quad * 4 + rr;
        const int col = n0 + wn * 64 + nt * 16 + n15;
        const float v = acc[mt][nt][rr] * scalev[rr];
        if constexpr (F32OUT)
          ((float*)Cv)[(size_t)row * N + col] = v;
        else
          ((unsigned short*)Cv)[(size_t)row * N + col] = f2bf(v);
      }
    }
  }
}

// ---------------------------------------------------------------------------
// q-proj + k-proj fused (separate launch from v_zero: alias safety, G16).
// ---------------------------------------------------------------------------
__global__ __launch_bounds__(256) void qk_proj(
    const unsigned short* __restrict__ x1h, const unsigned short* __restrict__ x1l,
    const unsigned short* __restrict__ Wqh, const unsigned short* __restrict__ Wql,
    const unsigned short* __restrict__ x2h, const unsigned short* __restrict__ x2l,
    const unsigned short* __restrict__ Wkh, const unsigned short* __restrict__ Wkl,
    unsigned short* __restrict__ qbf, unsigned short* __restrict__ kbf) {
  __shared__ __align__(16) unsigned short sAh[4096], sBh[4096], sAl[4096], sBl[4096];
  const int bi = blockIdx.x;
  if (bi < 96) {
    gemm_tile<true, true, false>(x1h, x1l, Wqh, Wql, qbf, B1, DMODEL, DMODEL,
                                 (bi / 6) * 128, (bi % 6) * 128, sAh, sBh, sAl, sBl);
  } else {
    const int b = bi - 96;
    gemm_tile<true, true, false>(x2h, x2l, Wkh, Wkl, kbf, B2, DMODEL, DMODEL,
                                 (b / 6) * 128, (b % 6) * 128, sAh, sBh, sAl, sBl);
  }
}

// ---------------------------------------------------------------------------
// v-proj (vt = Wv @ x2^T) + zero aoacc + zero lacc.
// ---------------------------------------------------------------------------
__global__ __launch_bounds__(256) void v_zero(
    const unsigned short* __restrict__ Wvh, const unsigned short* __restrict__ x2h,
    unsigned short* __restrict__ vtbf, float* __restrict__ aoacc,
    float* __restrict__ lacc) {
  __shared__ __align__(16) unsigned short sAh[4096], sBh[4096];
  const int bi = blockIdx.x;
  if (bi < 384) {
    gemm_tile<false, false, false>(Wvh, nullptr, x2h, nullptr, vtbf, DMODEL, B2,
                                   DMODEL, (bi / 64) * 128, (bi % 64) * 128,
                                   sAh, sBh, nullptr, nullptr);
  } else if (bi < 768) {
    const float4 z = {0.f, 0.f, 0.f, 0.f};
    float4* p = (float4*)aoacc + (size_t)(bi - 384) * 1024 + threadIdx.x;
    p[0] = z; p[256] = z; p[512] = z; p[768] = z;
  } else {
    const float4 z = {0.f, 0.f, 0.f, 0.f};
    float4* p = (float4*)lacc + (size_t)(bi - 768) * 1024 + threadIdx.x;
    p[0] = z; p[256] = z; p[512] = z; p[768] = z;
  }
}

// ---------------------------------------------------------------------------
// MFMA bf16 attention: 256 threads (2 qsub x 2 ksub), KC=64, KSPLIT=2.
// LDS 25600 B -> 6 blocks/CU by LDS.
// __launch_bounds__(256,4): VGPR cap 128 (gfx950 occupancy steps at 64/128 —
// (256,5) forced a 64-VGPR squeeze and 45 MB of scratch spill in R11/R4).
// Body ~76 VGPR -> 4 waves/SIMD -> 16 waves/CU (50%) with zero spill.
// ---------------------------------------------------------------------------
#define KC 64
#define KSPLIT 2
#define NCH (B2 / KSPLIT / KC)  // 64
#define PSTR 36

__global__ __launch_bounds__(256, 4) void attn_mfma(
    const unsigned short* __restrict__ qb, const unsigned short* __restrict__ kb,
    const unsigned short* __restrict__ vt, float* __restrict__ aoacc,
    float* __restrict__ lacc, const int* __restrict__ invt_p) {
  __shared__ __align__(16) unsigned short smem[12800];  // 25600 B exact
  unsigned short* Kl = smem;            // [64 keys][64 d] swizzled
  unsigned short* Vl = smem + 4096;     // [64 d][64 keys] swizzled
  unsigned short* Psl = smem + 8192;    // 4 waves x [32 q][PSTR] = 4608

  const float c2 = (float)invt_p[0] * 1.4426950408889634f;
  const int h = blockIdx.y;
  const int q0 = blockIdx.x * 64;
  const int tid = threadIdx.x;
  const int wave = tid >> 6;
  const int lane = tid & 63;
  const int qsub = wave >> 1;
  const int ksub = wave & 1;
  const int n15 = lane & 15;
  const int quad = lane >> 4;
  const int kz0 = blockIdx.z * (B2 / KSPLIT);

  unsigned short* Ps = &Psl[wave * 32 * PSTR];

  short8 qf[2][2];
#pragma unroll
  for (int qt = 0; qt < 2; ++qt)
#pragma unroll
    for (int ks = 0; ks < 2; ++ks) {
      const int qrow = q0 + qsub * 32 + qt * 16 + n15;
      qf[qt][ks] = *(const short8*)&qb[(size_t)qrow * DMODEL + h * DH + ks * 32 + quad * 8];
    }

  floatx4 oacc[2][4];
#pragma unroll
  for (int qt = 0; qt < 2; ++qt)
#pragma unroll
    for (int nt = 0; nt < 4; ++nt) oacc[qt][nt] = (floatx4){0.f, 0.f, 0.f, 0.f};
  float lsum[2] = {0.f, 0.f};

  ushort8 kr[2], vr[2];
#pragma unroll
  for (int i = 0; i < 2; ++i) {
    const int s = i * 256 + tid;
    const int key = s >> 3, cpk = s & 7, chk = cpk ^ (key & 7);
    kr[i] = *(const ushort8*)&kb[(size_t)(kz0 + key) * DMODEL + h * DH + chk * 8];
    vr[i] = *(const ushort8*)&vt[(size_t)(h * DH + key) * B2 + kz0 + chk * 8];
  }

  for (int c = 0; c < NCH; ++c) {
    __syncthreads();
#pragma unroll
    for (int i = 0; i < 2; ++i) {
      const int s = i * 256 + tid;
      const int key = s >> 3, cpk = s & 7;
      *(ushort8*)&Kl[key * 64 + cpk * 8] = kr[i];
      *(ushort8*)&Vl[key * 64 + cpk * 8] = vr[i];
    }
    if (c + 1 < NCH) {
      const int kc0n = kz0 + (c + 1) * KC;
#pragma unroll
      for (int i = 0; i < 2; ++i) {
        const int s = i * 256 + tid;
        const int key = s >> 3, cpk = s & 7, chk = cpk ^ (key & 7);
        kr[i] = *(const ushort8*)&kb[(size_t)(kc0n + key) * DMODEL + h * DH + chk * 8];
        vr[i] = *(const ushort8*)&vt[(size_t)(h * DH + key) * B2 + kc0n + chk * 8];
      }
    }
    __syncthreads();

#pragma unroll
    for (int kt = 0; kt < 2; ++kt) {
      floatx4 s0 = {0.f, 0.f, 0.f, 0.f}, s1 = {0.f, 0.f, 0.f, 0.f};
#pragma unroll
      for (int ks = 0; ks < 2; ++ks) {
        const int key = ksub * 32 + kt * 16 + n15;
        const int cp = (ks * 4 + quad) ^ (n15 & 7);
        const short8 kf = *(const short8*)&Kl[key * 64 + cp * 8];
        s0 = __builtin_amdgcn_mfma_f32_16x16x32_bf16(kf, qf[0][ks], s0, 0, 0, 0);
        s1 = __builtin_amdgcn_mfma_f32_16x16x32_bf16(kf, qf[1][ks], s1, 0, 0, 0);
      }
      ushort4v p0, p1;
#pragma unroll
      for (int r = 0; r < 4; ++r) {
        const float e0 = exp2f(fmaf(s0[r], c2, -c2));
        const float e1 = exp2f(fmaf(s1[r], c2, -c2));
        lsum[0] += e0;
        lsum[1] += e1;
        p0[r] = f2bf(e0);
        p1[r] = f2bf(e1);
      }
      *(ushort4v*)&Ps[(0 * 16 + n15) * PSTR + kt * 16 + quad * 4] = p0;
      *(ushort4v*)&Ps[(1 * 16 + n15) * PSTR + kt * 16 + quad * 4] = p1;
    }

    short8 pa[2];
#pragma unroll
    for (int qt = 0; qt < 2; ++qt)
      pa[qt] = *(const short8*)&Ps[(qt * 16 + n15) * PSTR + quad * 8];
#pragma unroll
    for (int nt = 0; nt < 4; ++nt) {
      const int dd = nt * 16 + n15;
      const int cp = (ksub * 4 + quad) ^ (n15 & 7);
      const short8 vf = *(const short8*)&Vl[dd * 64 + cp * 8];
      oacc[0][nt] = __builtin_amdgcn_mfma_f32_16x16x32_bf16(pa[0], vf, oacc[0][nt], 0, 0, 0);
      oacc[1][nt] = __builtin_amdgcn_mfma_f32_16x16x32_bf16(pa[1], vf, oacc[1][nt], 0, 0, 0);
    }
  }

#pragma unroll
  for (int qt = 0; qt < 2; ++qt) {
    float v = lsum[qt];
    v += __shfl_xor(v, 16, 64);
    v += __shfl_xor(v, 32, 64);
    lsum[qt] = v;
  }
  if (quad == 0) {
#pragma unroll
    for (int qt = 0; qt < 2; ++qt)
      atomicAdd(&lacc[(q0 + qsub * 32 + qt * 16 + n15) * NH + h], lsum[qt]);
  }

  __syncthreads();
  float* Osc = (float*)smem;
  if (ksub == 1) {
#pragma unroll
    for (int qt = 0; qt < 2; ++qt)
#pragma unroll
      for (int nt = 0; nt < 4; ++nt)
#pragma unroll
        for (int r = 0; r < 4; ++r) {
          const int row = qsub * 32 + qt * 16 + quad * 4 + r;
          Osc[row * 64 + nt * 16 + n15] = oacc[qt][nt][r];
        }
  }
  __syncthreads();
  if (ksub == 0) {
#pragma unroll
    for (int qt = 0; qt < 2; ++qt)
#pragma unroll
      for (int nt = 0; nt < 4; ++nt)
#pragma unroll
        for (int r = 0; r < 4; ++r) {
          const int row = qsub * 32 + qt * 16 + quad * 4 + r;
          const float v = oacc[qt][nt][r] + Osc[row * 64 + nt * 16 + n15];
          atomicAdd(&aoacc[(size_t)(q0 + row) * DMODEL + h * DH + nt * 16 + n15], v);
        }
  }
}

// ---------------------------------------------------------------------------
// Wo projection with fused ao-normalize A-staging (unchanged from R7).
// ---------------------------------------------------------------------------
__global__ __launch_bounds__(256) void wo_proj(
    const float* __restrict__ aoacc, const float* __restrict__ lacc,
    const unsigned short* __restrict__ Woh, float* __restrict__ woout) {
  __shared__ __align__(16) unsigned short sAh[4096], sBh[4096];
  const int bi = blockIdx.x;
  const int m0 = (bi / 6) * 128;
  const int n0 = (bi % 6) * 128;
  const int tid = threadIdx.x;
  const int wave = tid >> 6;
  const int lane = tid & 63;
  const int wm = wave >> 1;
  const int wn = wave & 1;
  const int n15 = lane & 15;
  const int quad = lane >> 4;
  const int srow = lane >> 2;
  const int cpl = (lane & 3) ^ (srow >> 2);

  floatx4 acc[4][4];
#pragma unroll
  for (int i = 0; i < 4; ++i)
#pragma unroll
    for (int j = 0; j < 4; ++j) acc[i][j] = (floatx4){0.f, 0.f, 0.f, 0.f};

  for (int k0 = 0; k0 < DMODEL; k0 += 32) {
    __syncthreads();
#pragma unroll
    for (int jj = 0; jj < 2; ++jj) {
      const int j = wave * 2 + jj;
      const int row = j * 16 + srow;
      const size_t ga = (size_t)(m0 + row) * DMODEL + k0 + cpl * 8;
      const float4 a0 = *(const float4*)&aoacc[ga];
      const float4 a1 = *(const float4*)&aoacc[ga + 4];
      const int head = (k0 + cpl * 8) >> 6;
      const float inv = 1.0f / lacc[(m0 + row) * NH + head];
      ushort8 ah = {f2bf(a0.x * inv), f2bf(a0.y * inv), f2bf(a0.z * inv),
                    f2bf(a0.w * inv), f2bf(a1.x * inv), f2bf(a1.y * inv),
                    f2bf(a1.z * inv), f2bf(a1.w * inv)};
      *(ushort8*)&sAh[j * 512 + lane * 8] = ah;
      gload16(Woh + (size_t)(n0 + row) * DMODEL + k0 + cpl * 8, &sBh[j * 512]);
    }
    __syncthreads();

    short8 afh[4];
#pragma unroll
    for (int mt = 0; mt < 4; ++mt) {
      const int row = wm * 64 + mt * 16 + n15;
      afh[mt] = *(const short8*)&sAh[row * 32 + ((quad ^ (n15 >> 2)) << 3)];
    }
#pragma unroll
    for (int nt = 0; nt < 4; ++nt) {
      const int row = wn * 64 + nt * 16 + n15;
      const short8 bfh = *(const short8*)&sBh[row * 32 + ((quad ^ (n15 >> 2)) << 3)];
#pragma unroll
      for (int mt = 0; mt < 4; ++mt)
        acc[mt][nt] = __builtin_amdgcn_mfma_f32_16x16x32_bf16(afh[mt], bfh, acc[mt][nt], 0, 0, 0);
    }
  }

#pragma unroll
  for (int mt = 0; mt < 4; ++mt)
#pragma unroll
    for (int nt = 0; nt < 4; ++nt)
#pragma unroll
      for (int rr = 0; rr < 4; ++rr) {
        const int row = m0 + wm * 64 + mt * 16 + quad * 4 + rr;
        const int col = n0 + wn * 64 + nt * 16 + n15;
        woout[(size_t)row * DMODEL + col] = acc[mt][nt][rr];
      }
}

// ---------------------------------------------------------------------------
__global__ __launch_bounds__(256) void l2norm_rows768_out(
    const float* __restrict__ x, float* __restrict__ out) {
  const int row = blockIdx.x;
  const float* xr = &x[(size_t)row * DMODEL];
  float ss = 0.0f;
  float vals[3];
#pragma unroll
  for (int i = 0; i < 3; ++i) {
    vals[i] = xr[threadIdx.x + i * 256];
    ss += vals[i] * vals[i];
  }
#pragma unroll
  for (int off = 32; off > 0; off >>= 1) ss += __shfl_xor(ss, off, 64);
  __shared__ float ws[4];
  if ((threadIdx.x & 63) == 0) ws[threadIdx.x >> 6] = ss;
  __syncthreads();
  const float tot = ws[0] + ws[1] + ws[2] + ws[3];
  const float sc = 1.0f / fmaxf(sqrtf(tot), 1e-12f);
  float* orow = &out[(size_t)row * DMODEL];
#pragma unroll
  for (int i = 0; i < 3; ++i) orow[threadIdx.x + i * 256] = vals[i] * sc;
}

// ---------------------------------------------------------------------------
extern "C" void kernel_launch(void* const* d_in, const int* in_sizes, int n_in,
                              void* d_out, int out_size, void* d_ws,
                              size_t ws_size, hipStream_t stream) {
  const float* x1 = (const float*)d_in[0];
  const float* x2 = (const float*)d_in[1];
  const float* Wq = (const float*)d_in[2];
  const float* Wk = (const float*)d_in[3];
  const float* Wv = (const float*)d_in[4];
  const float* Wo = (const float*)d_in[5];
  const int* invt = (const int*)d_in[6];
  float* outp = (float*)d_out;

  // Aliases cross LAUNCH boundaries only (G16).
  char* ws = (char*)d_ws;
  unsigned short* x1h = (unsigned short*)(ws + 0);
  unsigned short* x1l = (unsigned short*)(ws + 3145728);
  unsigned short* x2h = (unsigned short*)(ws + 6291456);
  unsigned short* x2l = (unsigned short*)(ws + 18874368);
  unsigned short* Wqh = (unsigned short*)(ws + 31457280);
  unsigned short* Wql = (unsigned short*)(ws + 32636928);
  unsigned short* Wkh = (unsigned short*)(ws + 33816576);
  unsigned short* Wkl = (unsigned short*)(ws + 34996224);
  unsigned short* Wvh = (unsigned short*)(ws + 36175872);
  unsigned short* Woh = (unsigned short*)(ws + 37355520);
  unsigned short* q_bf = (unsigned short*)(ws + 38535168);
  unsigned short* k_bf = (unsigned short*)(ws + 41680896);
  float* lacc = (float*)(ws + 54263808);
  float* aoacc = (float*)(ws + 0);
  unsigned short* vt_bf = (unsigned short*)(ws + 18874368);
  float* woout = (float*)(ws + 9437184);

  prep_all<<<9984, 256, 0, stream>>>(x1, x1h, x1l, x2, x2h, x2l, Wq, Wqh, Wql,
                                     Wk, Wkh, Wkl, Wv, Wvh, Wo, Woh);
  qk_proj<<<480, 256, 0, stream>>>(x1h, x1l, Wqh, Wql, x2h, x2l, Wkh, Wkl,
                                   q_bf, k_bf);
  v_zero<<<774, 256, 0, stream>>>(Wvh, x2h, vt_bf, aoacc, lacc);
  attn_mfma<<<dim3(B1 / 64, NH, KSPLIT), 256, 0, stream>>>(q_bf, k_bf, vt_bf,
                                                           aoacc, lacc, invt);
  wo_proj<<<96, 256, 0, stream>>>(aoacc, lacc, Woh, woout);
  l2norm_rows768_out<<<B1, 256, 0, stream>>>(woout, outp);
}